// Round 1
// baseline (87.921 us; speedup 1.0000x reference)
//
#include <hip/hip_runtime.h>
#include <math.h>

// Problem constants (reference: B=4, L=2048)
#define LQ 2048
#define NB 4
#define NSEG 2047          // L-1 segments per path
#define SEG_PAD 2048       // padded segment count
#define SEG_STRIDE 12      // floats per segment record: dr(3), r(3), m(3), pad(3)
#define WS_ACC_FLOATS 16   // ws[0..3] = per-batch sums; rest padding/alignment

// ws layout (floats):
//   [0..3]        per-batch partial sums (zeroed by seg_kernel)
//   [16 ...]      segment records: [path(2)][b(4)][i(SEG_PAD)][SEG_STRIDE]
// total: 16 + 2*4*2048*12 floats = ~786.5 KB

__device__ __forceinline__ float rcp_fast(float x)  { return __builtin_amdgcn_rcpf(x); }
__device__ __forceinline__ float sqrt_fast(float x) { return __builtin_amdgcn_sqrtf(x); }

// ---------------------------------------------------------------------------
// Kernel A: build segment records {dr, r, m = r x dr} for both paths.
// One thread per (path, batch, segment). 2*4*2048 = 16384 threads.
// ---------------------------------------------------------------------------
__global__ __launch_bounds__(256) void seg_kernel(const float4* __restrict__ qa,
                                                  const float4* __restrict__ qb,
                                                  float* ws) {
    int tid = blockIdx.x * 256 + threadIdx.x;
    if (tid < WS_ACC_FLOATS) ws[tid] = 0.0f;   // zero accumulators (ws re-poisoned each call)

    int i  = tid & (LQ - 1);
    int bp = tid >> 11;         // 0..7 : (path<<2) | batch
    int b  = bp & 3;
    int p  = bp >> 2;
    if (i >= NSEG) return;

    const float4* q = p ? qb : qa;
    float4 q0 = q[b * LQ + i];
    float4 q1 = q[b * LQ + i + 1];

    // normalize quaternions; path point = imaginary parts (components 1,2,3) * 1/(||q||+1e-12)
    float n0 = sqrt_fast(fmaf(q0.x, q0.x, fmaf(q0.y, q0.y, fmaf(q0.z, q0.z, q0.w * q0.w))));
    float s0 = rcp_fast(n0 + 1e-12f);
    float ax = q0.y * s0, ay = q0.z * s0, az = q0.w * s0;

    float n1 = sqrt_fast(fmaf(q1.x, q1.x, fmaf(q1.y, q1.y, fmaf(q1.z, q1.z, q1.w * q1.w))));
    float s1 = rcp_fast(n1 + 1e-12f);
    float bx = q1.y * s1, by = q1.z * s1, bz = q1.w * s1;

    float drx = bx - ax, dry = by - ay, drz = bz - az;
    float rx = 0.5f * (ax + bx), ry = 0.5f * (ay + by), rz = 0.5f * (az + bz);
    // m = r x dr
    float mx = ry * drz - rz * dry;
    float my = rz * drx - rx * drz;
    float mz = rx * dry - ry * drx;

    float* rec = ws + WS_ACC_FLOATS + (size_t)((bp * SEG_PAD + i) * SEG_STRIDE);
    float4* r4 = (float4*)rec;
    r4[0] = make_float4(drx, dry, drz, rx);
    r4[1] = make_float4(ry, rz, mx, my);
    r4[2] = make_float4(mz, 0.0f, 0.0f, 0.0f);
}

// ---------------------------------------------------------------------------
// Kernel B: all-pairs sum. numerator factorization:
//   (r_a - r_b) . (dr_a x dr_b) = m_a . dr_b + dr_a . m_b,  m = r x dr
// Grid: (jc=256, itile=2, b=4). Block 256 threads; each thread owns 4 i's
// (stride 256 within a 1024-i tile) and iterates an 8-wide j chunk.
// ---------------------------------------------------------------------------
#define MI 4
#define JC 8

__global__ __launch_bounds__(256) void pair_kernel(const float* __restrict__ seg_base,
                                                   float* acc_out) {
    int jc    = blockIdx.x;    // 0..255
    int itile = blockIdx.y;    // 0..1
    int b     = blockIdx.z;    // 0..3
    int t     = threadIdx.x;

    const float* segA = seg_base + WS_ACC_FLOATS + (size_t)((0 * NB + b) * SEG_PAD) * SEG_STRIDE;
    const float* segB = seg_base + WS_ACC_FLOATS + (size_t)((1 * NB + b) * SEG_PAD) * SEG_STRIDE;

    float dra[MI][3], ra[MI][3], ma[MI][3];
#pragma unroll
    for (int k = 0; k < MI; k++) {
        int i = itile * 1024 + k * 256 + t;
        if (i < NSEG) {
            const float4* r4 = (const float4*)(segA + (size_t)i * SEG_STRIDE);
            float4 A = r4[0], B = r4[1], C = r4[2];
            dra[k][0] = A.x; dra[k][1] = A.y; dra[k][2] = A.z;
            ra[k][0]  = A.w; ra[k][1]  = B.x; ra[k][2]  = B.y;
            ma[k][0]  = B.z; ma[k][1]  = B.w; ma[k][2]  = C.x;
        } else {
            // zero record contributes exactly 0 (num==0, inv finite)
#pragma unroll
            for (int c = 0; c < 3; c++) { dra[k][c] = 0.f; ra[k][c] = 0.f; ma[k][c] = 0.f; }
        }
    }

    float acc = 0.0f;
    int j0 = jc * JC;
#pragma unroll
    for (int jj = 0; jj < JC; jj++) {
        int j = j0 + jj;
        if (j >= NSEG) break;  // block-uniform branch
        const float4* r4 = (const float4*)(segB + (size_t)j * SEG_STRIDE);
        float4 A = r4[0], B = r4[1], C = r4[2];
        float drbx = A.x, drby = A.y, drbz = A.z;
        float rbx  = A.w, rby  = B.x, rbz  = B.y;
        float mbx  = B.z, mby  = B.w, mbz  = C.x;
#pragma unroll
        for (int k = 0; k < MI; k++) {
            float dx = ra[k][0] - rbx;
            float dy = ra[k][1] - rby;
            float dz = ra[k][2] - rbz;
            float d2 = fmaf(dx, dx, fmaf(dy, dy, dz * dz));
            float s  = sqrt_fast(d2) + 1e-6f;
            float num = fmaf(ma[k][0], drbx,
                        fmaf(ma[k][1], drby,
                        fmaf(ma[k][2], drbz,
                        fmaf(dra[k][0], mbx,
                        fmaf(dra[k][1], mby, dra[k][2] * mbz)))));
            float inv = rcp_fast(s * s * s);
            acc = fmaf(num, inv, acc);
        }
    }

    // block reduction: wave64 shuffle, then LDS across 4 waves
#pragma unroll
    for (int off = 32; off > 0; off >>= 1) acc += __shfl_down(acc, off, 64);
    __shared__ float wsum[4];
    int lane = t & 63, w = t >> 6;
    if (lane == 0) wsum[w] = acc;
    __syncthreads();
    if (t == 0) {
        float tot = wsum[0] + wsum[1] + wsum[2] + wsum[3];
        atomicAdd(&acc_out[b], tot);
    }
}

// ---------------------------------------------------------------------------
// Kernel C: out = mean_b |S_b| / (4*pi)
// ---------------------------------------------------------------------------
__global__ void finalize_kernel(const float* ws, float* out) {
    if (threadIdx.x == 0) {
        float s = 0.0f;
        for (int b = 0; b < NB; b++) s += fabsf(ws[b]);
        out[0] = s * (1.0f / NB) * (1.0f / (4.0f * 3.14159265358979323846f));
    }
}

extern "C" void kernel_launch(void* const* d_in, const int* in_sizes, int n_in,
                              void* d_out, int out_size, void* d_ws, size_t ws_size,
                              hipStream_t stream) {
    const float4* qa = (const float4*)d_in[0];  // genomic_quats [B,L,4] f32
    const float4* qb = (const float4*)d_in[1];  // code_quats    [B,L,4] f32
    float* ws  = (float*)d_ws;
    float* out = (float*)d_out;

    seg_kernel<<<dim3(64), dim3(256), 0, stream>>>(qa, qb, ws);
    pair_kernel<<<dim3(256, 2, NB), dim3(256), 0, stream>>>(ws, ws);
    finalize_kernel<<<dim3(1), dim3(64), 0, stream>>>(ws, out);
}

// Round 2
// 66.342 us; speedup vs baseline: 1.3253x; 1.3253x over previous
//
#include <hip/hip_runtime.h>
#include <math.h>

// Problem constants (reference: B=4, L=2048)
#define LQ 2048
#define NB 4
#define NSEG 2047          // L-1 segments per path
#define MI 4               // i-segments per thread
#define JC 8               // j-segments per block
#define PARTIALS_PER_B 512 // itile(2) * jc(256) partial sums per batch

__device__ __forceinline__ float rcp_fast(float x)  { return __builtin_amdgcn_rcpf(x); }
__device__ __forceinline__ float rsq_fast(float x)  { return __builtin_amdgcn_rsqf(x); }

// Build one segment record from two quaternions:
//   p = normalized(q).yzw ; dr = p1-p0 ; r = 0.5(p0+p1) ; m = r x dr
__device__ __forceinline__ void make_seg(float4 q0, float4 q1,
                                         float dr[3], float r[3], float m[3]) {
    float n2a = fmaf(q0.x, q0.x, fmaf(q0.y, q0.y, fmaf(q0.z, q0.z, q0.w * q0.w)));
    float s0  = rsq_fast(n2a);                 // ~ 1/(||q||+1e-12) for ||q||~O(1)
    float ax = q0.y * s0, ay = q0.z * s0, az = q0.w * s0;
    float n2b = fmaf(q1.x, q1.x, fmaf(q1.y, q1.y, fmaf(q1.z, q1.z, q1.w * q1.w)));
    float s1  = rsq_fast(n2b);
    float bx = q1.y * s1, by = q1.z * s1, bz = q1.w * s1;
    dr[0] = bx - ax; dr[1] = by - ay; dr[2] = bz - az;
    r[0] = 0.5f * (ax + bx); r[1] = 0.5f * (ay + by); r[2] = 0.5f * (az + bz);
    m[0] = r[1] * dr[2] - r[2] * dr[1];
    m[1] = r[2] * dr[0] - r[0] * dr[2];
    m[2] = r[0] * dr[1] - r[1] * dr[0];
}

// ---------------------------------------------------------------------------
// Fused kernel: recompute segments on the fly, all-pairs Gauss sum.
// num = (r_a - r_b).(dr_a x dr_b) = m_a.dr_b + dr_a.m_b  with m = r x dr.
// Grid (jc=256, itile=2, b=4), block 256. Thread owns MI=4 i's; block owns
// JC=8 j's staged in LDS by threads 0..7. Each block writes one partial slot
// (no atomics, no pre-zeroed memory needed).
// ---------------------------------------------------------------------------
__global__ __launch_bounds__(256) void pair_fused(const float4* __restrict__ qa,
                                                  const float4* __restrict__ qb,
                                                  float* __restrict__ partials) {
    const int jc    = blockIdx.x;   // 0..255
    const int itile = blockIdx.y;   // 0..1
    const int b     = blockIdx.z;   // 0..3
    const int t     = threadIdx.x;

    // --- j-records (block-uniform) into LDS, built by threads 0..7 ---
    __shared__ float js[JC][12];    // drb(3), rb(3), mb(3), pad(3)
    if (t < JC) {
        int j = jc * JC + t;
        float dr[3] = {0.f, 0.f, 0.f}, r[3] = {0.f, 0.f, 0.f}, m[3] = {0.f, 0.f, 0.f};
        if (j < NSEG) {
            float4 q0 = qb[b * LQ + j];
            float4 q1 = qb[b * LQ + j + 1];
            make_seg(q0, q1, dr, r, m);
        }
        js[t][0] = dr[0]; js[t][1] = dr[1]; js[t][2] = dr[2];
        js[t][3] = r[0];  js[t][4] = r[1];  js[t][5] = r[2];
        js[t][6] = m[0];  js[t][7] = m[1];  js[t][8] = m[2];
        js[t][9] = 0.f;   js[t][10] = 0.f;  js[t][11] = 0.f;
    }

    // --- i-records (per-thread, coalesced quat loads) ---
    float dra[MI][3], ra[MI][3], ma[MI][3];
#pragma unroll
    for (int k = 0; k < MI; k++) {
        int i = itile * 1024 + k * 256 + t;
        if (i < NSEG) {
            float4 q0 = qa[b * LQ + i];
            float4 q1 = qa[b * LQ + i + 1];
            make_seg(q0, q1, dra[k], ra[k], ma[k]);
        } else {
            // zero record: num==0 exactly, d2 = |rb|^2 + 1e-12 finite -> contributes 0
#pragma unroll
            for (int c = 0; c < 3; c++) { dra[k][c] = 0.f; ra[k][c] = 0.f; ma[k][c] = 0.f; }
        }
    }

    __syncthreads();

    float acc = 0.0f;
#pragma unroll
    for (int jj = 0; jj < JC; jj++) {
        float drbx = js[jj][0], drby = js[jj][1], drbz = js[jj][2];
        float rbx  = js[jj][3], rby  = js[jj][4], rbz  = js[jj][5];
        float mbx  = js[jj][6], mby  = js[jj][7], mbz  = js[jj][8];
#pragma unroll
        for (int k = 0; k < MI; k++) {
            float dx = ra[k][0] - rbx;
            float dy = ra[k][1] - rby;
            float dz = ra[k][2] - rbz;
            float d2 = fmaf(dx, dx, fmaf(dy, dy, fmaf(dz, dz, 1e-12f)));
            float rs = rsq_fast(d2);             // 1/(dist); eps folded into d2
            float inv3 = rs * rs * rs;           // 1/dist^3
            float num = fmaf(ma[k][0], drbx,
                        fmaf(ma[k][1], drby,
                        fmaf(ma[k][2], drbz,
                        fmaf(dra[k][0], mbx,
                        fmaf(dra[k][1], mby, dra[k][2] * mbz)))));
            acc = fmaf(num, inv3, acc);
        }
    }

    // --- block reduction: wave64 shuffle, then LDS across 4 waves ---
#pragma unroll
    for (int off = 32; off > 0; off >>= 1) acc += __shfl_down(acc, off, 64);
    __shared__ float wsum[4];
    int lane = t & 63, w = t >> 6;
    if (lane == 0) wsum[w] = acc;
    __syncthreads();
    if (t == 0) {
        partials[b * PARTIALS_PER_B + itile * 256 + jc] =
            wsum[0] + wsum[1] + wsum[2] + wsum[3];
    }
}

// ---------------------------------------------------------------------------
// Finalize: wave w reduces batch w's 512 partials; out = mean_b |S_b| / (4*pi)
// ---------------------------------------------------------------------------
__global__ __launch_bounds__(256) void finalize_kernel(const float* __restrict__ partials,
                                                       float* __restrict__ out) {
    int t = threadIdx.x;
    int w = t >> 6, lane = t & 63;
    float s = 0.0f;
#pragma unroll
    for (int r = 0; r < PARTIALS_PER_B / 64; r++)
        s += partials[w * PARTIALS_PER_B + r * 64 + lane];
#pragma unroll
    for (int off = 32; off > 0; off >>= 1) s += __shfl_down(s, off, 64);
    __shared__ float sb[4];
    if (lane == 0) sb[w] = s;
    __syncthreads();
    if (t == 0) {
        float tot = fabsf(sb[0]) + fabsf(sb[1]) + fabsf(sb[2]) + fabsf(sb[3]);
        out[0] = tot * (1.0f / NB) * (1.0f / (4.0f * 3.14159265358979323846f));
    }
}

extern "C" void kernel_launch(void* const* d_in, const int* in_sizes, int n_in,
                              void* d_out, int out_size, void* d_ws, size_t ws_size,
                              hipStream_t stream) {
    const float4* qa = (const float4*)d_in[0];  // genomic_quats [B,L,4] f32
    const float4* qb = (const float4*)d_in[1];  // code_quats    [B,L,4] f32
    float* partials = (float*)d_ws;             // 2048 floats; fully overwritten
    float* out = (float*)d_out;

    pair_fused<<<dim3(256, 2, NB), dim3(256), 0, stream>>>(qa, qb, partials);
    finalize_kernel<<<dim3(1), dim3(256), 0, stream>>>(partials, out);
}

// Round 3
// 65.489 us; speedup vs baseline: 1.3425x; 1.0130x over previous
//
#include <hip/hip_runtime.h>
#include <math.h>

// Problem constants (reference: B=4, L=2048)
#define LQ 2048
#define NB 4
#define NSEG 2047
#define MI 4               // i-segments per thread
#define JC 16              // j-segments per block
#define NJC 128            // j-chunks: JC*NJC = 2048 covers NSEG
#define NITILE 2           // i tiles of 1024
#define PARTIALS_PER_B (NJC * NITILE)   // 256 partials per batch

typedef float v2f __attribute__((ext_vector_type(2)));

__device__ __forceinline__ float rsq_fast(float x) { return __builtin_amdgcn_rsqf(x); }
__device__ __forceinline__ v2f fma2(v2f a, v2f b, v2f c) { return __builtin_elementwise_fma(a, b, c); }
__device__ __forceinline__ v2f splat2(float s) { v2f r; r.x = s; r.y = s; return r; }

// Build one segment record from two quaternions:
//   p = normalized(q).yzw ; dr = p1-p0 ; r = 0.5(p0+p1) ; m = r x dr
__device__ __forceinline__ void make_seg(float4 q0, float4 q1,
                                         float dr[3], float r[3], float m[3]) {
    float n2a = fmaf(q0.x, q0.x, fmaf(q0.y, q0.y, fmaf(q0.z, q0.z, q0.w * q0.w)));
    float s0  = rsq_fast(n2a);
    float ax = q0.y * s0, ay = q0.z * s0, az = q0.w * s0;
    float n2b = fmaf(q1.x, q1.x, fmaf(q1.y, q1.y, fmaf(q1.z, q1.z, q1.w * q1.w)));
    float s1  = rsq_fast(n2b);
    float bx = q1.y * s1, by = q1.z * s1, bz = q1.w * s1;
    dr[0] = bx - ax; dr[1] = by - ay; dr[2] = bz - az;
    r[0] = 0.5f * (ax + bx); r[1] = 0.5f * (ay + by); r[2] = 0.5f * (az + bz);
    m[0] = r[1] * dr[2] - r[2] * dr[1];
    m[1] = r[2] * dr[0] - r[0] * dr[2];
    m[2] = r[0] * dr[1] - r[1] * dr[0];
}

// ---------------------------------------------------------------------------
// Fused all-pairs Gauss sum, packed-f32 inner loop (2 j's per instruction).
// num = (r_a - r_b).(dr_a x dr_b) = m_a.dr_b + dr_a.m_b  with m = r x dr.
// Grid (jc=128, itile=2, b=4) = 1024 blocks, 256 threads.
// Thread owns MI=4 i's; block owns JC=16 j's staged SoA in LDS (v2f
// broadcast reads). Each block writes one partial slot (no atomics).
// ---------------------------------------------------------------------------
__global__ __launch_bounds__(256) void pair_fused(const float4* __restrict__ qa,
                                                  const float4* __restrict__ qb,
                                                  float* __restrict__ partials) {
    const int jc    = blockIdx.x;   // 0..127
    const int itile = blockIdx.y;   // 0..1
    const int b     = blockIdx.z;   // 0..3
    const int t     = threadIdx.x;

    // --- j-records SoA in LDS: fields {drb.xyz, rb.xyz, mb.xyz} ---
    __shared__ __align__(8) float jsoa[9][JC];
    if (t < JC) {
        int j = jc * JC + t;
        float dr[3] = {0.f,0.f,0.f}, r[3] = {0.f,0.f,0.f}, m[3] = {0.f,0.f,0.f};
        if (j < NSEG) {
            make_seg(qb[b * LQ + j], qb[b * LQ + j + 1], dr, r, m);
        }
        jsoa[0][t] = dr[0]; jsoa[1][t] = dr[1]; jsoa[2][t] = dr[2];
        jsoa[3][t] = r[0];  jsoa[4][t] = r[1];  jsoa[5][t] = r[2];
        jsoa[6][t] = m[0];  jsoa[7][t] = m[1];  jsoa[8][t] = m[2];
    }

    // --- i-records per thread (coalesced quat loads, L3-resident) ---
    float dra[MI][3], ra[MI][3], ma[MI][3];
#pragma unroll
    for (int k = 0; k < MI; k++) {
        int i = itile * 1024 + k * 256 + t;
        if (i < NSEG) {
            make_seg(qa[b * LQ + i], qa[b * LQ + i + 1], dra[k], ra[k], ma[k]);
        } else {
            // zero record: num == 0 exactly, d2 = eps -> contributes 0
#pragma unroll
            for (int c = 0; c < 3; c++) { dra[k][c] = 0.f; ra[k][c] = 0.f; ma[k][c] = 0.f; }
        }
    }

    __syncthreads();

    v2f acc = splat2(0.0f);
#pragma unroll
    for (int jj2 = 0; jj2 < JC / 2; jj2++) {
        v2f drbx = *(const v2f*)&jsoa[0][jj2 * 2];
        v2f drby = *(const v2f*)&jsoa[1][jj2 * 2];
        v2f drbz = *(const v2f*)&jsoa[2][jj2 * 2];
        v2f rbx  = *(const v2f*)&jsoa[3][jj2 * 2];
        v2f rby  = *(const v2f*)&jsoa[4][jj2 * 2];
        v2f rbz  = *(const v2f*)&jsoa[5][jj2 * 2];
        v2f mbx  = *(const v2f*)&jsoa[6][jj2 * 2];
        v2f mby  = *(const v2f*)&jsoa[7][jj2 * 2];
        v2f mbz  = *(const v2f*)&jsoa[8][jj2 * 2];
#pragma unroll
        for (int k = 0; k < MI; k++) {
            v2f dx = splat2(ra[k][0]) - rbx;
            v2f dy = splat2(ra[k][1]) - rby;
            v2f dz = splat2(ra[k][2]) - rbz;
            v2f d2 = fma2(dx, dx, fma2(dy, dy, fma2(dz, dz, splat2(1e-12f))));
            v2f rs; rs.x = rsq_fast(d2.x); rs.y = rsq_fast(d2.y);
            v2f inv3 = (rs * rs) * rs;      // 1/dist^3
            v2f num = fma2(splat2(ma[k][0]), drbx,
                      fma2(splat2(ma[k][1]), drby,
                      fma2(splat2(ma[k][2]), drbz,
                      fma2(splat2(dra[k][0]), mbx,
                      fma2(splat2(dra[k][1]), mby, splat2(dra[k][2]) * mbz)))));
            acc = fma2(num, inv3, acc);
        }
    }
    float a = acc.x + acc.y;

    // --- block reduction: wave64 shuffle, then LDS across 4 waves ---
#pragma unroll
    for (int off = 32; off > 0; off >>= 1) a += __shfl_down(a, off, 64);
    __shared__ float wsum[4];
    int lane = t & 63, w = t >> 6;
    if (lane == 0) wsum[w] = a;
    __syncthreads();
    if (t == 0) {
        partials[b * PARTIALS_PER_B + itile * NJC + jc] =
            wsum[0] + wsum[1] + wsum[2] + wsum[3];
    }
}

// ---------------------------------------------------------------------------
// Finalize: wave w reduces batch w's 256 partials; out = mean_b |S_b|/(4*pi)
// ---------------------------------------------------------------------------
__global__ __launch_bounds__(256) void finalize_kernel(const float* __restrict__ partials,
                                                       float* __restrict__ out) {
    int t = threadIdx.x;
    int w = t >> 6, lane = t & 63;
    float s = 0.0f;
#pragma unroll
    for (int r = 0; r < PARTIALS_PER_B / 64; r++)
        s += partials[w * PARTIALS_PER_B + r * 64 + lane];
#pragma unroll
    for (int off = 32; off > 0; off >>= 1) s += __shfl_down(s, off, 64);
    __shared__ float sb[4];
    if (lane == 0) sb[w] = s;
    __syncthreads();
    if (t == 0) {
        float tot = fabsf(sb[0]) + fabsf(sb[1]) + fabsf(sb[2]) + fabsf(sb[3]);
        out[0] = tot * (1.0f / NB) * (1.0f / (4.0f * 3.14159265358979323846f));
    }
}

extern "C" void kernel_launch(void* const* d_in, const int* in_sizes, int n_in,
                              void* d_out, int out_size, void* d_ws, size_t ws_size,
                              hipStream_t stream) {
    const float4* qa = (const float4*)d_in[0];  // genomic_quats [B,L,4] f32
    const float4* qb = (const float4*)d_in[1];  // code_quats    [B,L,4] f32
    float* partials = (float*)d_ws;             // 1024 floats; fully overwritten
    float* out = (float*)d_out;

    pair_fused<<<dim3(NJC, NITILE, NB), dim3(256), 0, stream>>>(qa, qb, partials);
    finalize_kernel<<<dim3(1), dim3(256), 0, stream>>>(partials, out);
}